// Round 8
// baseline (284.139 us; speedup 1.0000x reference)
//
#include <hip/hip_runtime.h>

#define WW 128
#define HWSZ 16384
#define CC 64
#define NPLANE 512
#define NCHW 8388608      // 8*64*128*128
#define BN_EPS 1e-5f

typedef float v4f __attribute__((ext_vector_type(4)));

// One persistent fused kernel. Grid = 2048 blocks = 8 blocks/CU * 256 CU, all
// co-resident (launch_bounds(256,8) caps VGPR<=64; LDS 17.7KB <= 20KB/block).
// Block (plane, band) owns 32 rows. Phase1 stages rows+halos to LDS and
// publishes the band sum; per-image counter + spin forms the cross-block sync.
__global__ __launch_bounds__(256, 8) void dc_fused_kernel(
    const float* __restrict__ x,
    const float* __restrict__ conv_w,
    const float* __restrict__ gamma,
    const float* __restrict__ beta,
    const float* __restrict__ bn_mean,
    const float* __restrict__ bn_var,
    float* __restrict__ out,
    float* __restrict__ partial,     // [8][64][4] band sums
    int* __restrict__ cnt)           // [8] per-image arrival counters
{
    __shared__ __align__(16) float tile[34 * WW];   // rows 0..31 owned, 32=top halo, 33=bottom halo
    __shared__ float smean[CC];
    __shared__ float lv[9];
    __shared__ float wsum[4];

    const int blk   = blockIdx.x;
    const int plane = blk >> 2;           // n*64 + c
    const int band  = blk & 3;
    const int n = plane >> 6;
    const int c = plane & 63;
    const int b0 = band * 32;
    const int tid = threadIdx.x;
    const float* xpl = x + (size_t)plane * HWSZ;

    // ---------------- Phase 1: stage band to LDS + band sum ----------------
    const v4f* src = (const v4f*)(xpl + (size_t)b0 * WW);
    float s = 0.f;
#pragma unroll
    for (int i = 0; i < 4; ++i) {
        const int idx = tid + i * 256;    // v4f index within the 32-row band
        v4f v = src[idx];
        ((v4f*)tile)[idx] = v;
        s += v.x + v.y + v.z + v.w;
    }
    if (tid < 64) {                       // halo rows (reflected at image edges)
        const int hr   = (tid < 32) ? (b0 - 1) : (b0 + 32);
        const int slot = (tid < 32) ? 32 : 33;
        const int q    = tid & 31;
        const int RR = (hr < 0) ? 1 : ((hr > 127) ? 126 : hr);
        v4f v = *(const v4f*)(xpl + (size_t)RR * WW + q * 4);
        ((v4f*)tile)[slot * 32 + q] = v;
    }
    for (int off = 32; off > 0; off >>= 1)
        s += __shfl_down(s, off, 64);
    if ((tid & 63) == 0) wsum[tid >> 6] = s;
    __syncthreads();

    if (tid == 0) {
        const float tot = wsum[0] + wsum[1] + wsum[2] + wsum[3];
        __hip_atomic_store(&partial[plane * 4 + band], tot,
                           __ATOMIC_RELAXED, __HIP_MEMORY_SCOPE_AGENT);
        __hip_atomic_fetch_add(&cnt[n], 1, __ATOMIC_RELEASE, __HIP_MEMORY_SCOPE_AGENT);
        // all 2048 blocks are co-resident -> spin cannot deadlock
        while (__hip_atomic_load(&cnt[n], __ATOMIC_ACQUIRE, __HIP_MEMORY_SCOPE_AGENT) < 256)
            __builtin_amdgcn_s_sleep(1);
    }
    __syncthreads();

    // ------------- Phase 2: channel means -> 9 logits -> softmax -------------
    if (tid < CC) {
        const float* pp = partial + n * 256 + tid * 4;
        float t0 = __hip_atomic_load(pp + 0, __ATOMIC_RELAXED, __HIP_MEMORY_SCOPE_AGENT);
        float t1 = __hip_atomic_load(pp + 1, __ATOMIC_RELAXED, __HIP_MEMORY_SCOPE_AGENT);
        float t2 = __hip_atomic_load(pp + 2, __ATOMIC_RELAXED, __HIP_MEMORY_SCOPE_AGENT);
        float t3 = __hip_atomic_load(pp + 3, __ATOMIC_RELAXED, __HIP_MEMORY_SCOPE_AGENT);
        smean[tid] = (t0 + t1 + t2 + t3) * (1.0f / 16384.0f);
    }
    __syncthreads();
    if (tid < 144) {
        const int j    = tid >> 4;        // tap 0..8
        const int part = tid & 15;        // 16 lanes per tap
        const int jj = c * 9 + j;
        v4f mv = *(const v4f*)(smean + part * 4);
        v4f wv = *(const v4f*)(conv_w + (size_t)jj * CC + part * 4);
        float d = mv.x * wv.x + mv.y * wv.y + mv.z * wv.z + mv.w * wv.w;
        d += __shfl_down(d, 8, 16);
        d += __shfl_down(d, 4, 16);
        d += __shfl_down(d, 2, 16);
        d += __shfl_down(d, 1, 16);
        if (part == 0) {
            const float g = gamma[jj] * rsqrtf(bn_var[jj] + BN_EPS);
            lv[j] = (d - bn_mean[jj]) * g + beta[jj];
        }
    }
    __syncthreads();

    float w9[9];
    {
        float m = lv[0];
#pragma unroll
        for (int t = 1; t < 9; ++t) m = fmaxf(m, lv[t]);
        float den = 0.f;
        float e[9];
#pragma unroll
        for (int t = 0; t < 9; ++t) { e[t] = __expf(lv[t] - m); den += e[t]; }
        const float inv = 1.0f / den;
#pragma unroll
        for (int t = 0; t < 9; ++t) w9[t] = e[t] * inv;
    }

    // ---------------- Phase 3: conv from LDS, NT-store results ----------------
    const int g  = tid >> 5;              // row group 0..7 (4 rows each)
    const int q  = tid & 31;
    const int w0 = q * 4;

#pragma unroll
    for (int i = 0; i < 4; ++i) {
        const int h = b0 + g * 4 + i;
        const int sP = (h == b0)      ? 32 : (h - 1 - b0);
        const int sC = h - b0;
        const int sN = (h == b0 + 31) ? 33 : (h + 1 - b0);

        v4f cP = ((const v4f*)tile)[sP * 32 + q];
        v4f cC = ((const v4f*)tile)[sC * 32 + q];
        v4f cN = ((const v4f*)tile)[sN * 32 + q];

        float eP0 = __shfl_up(cP.w, 1, 32), eP1 = __shfl_down(cP.x, 1, 32);
        float eC0 = __shfl_up(cC.w, 1, 32), eC1 = __shfl_down(cC.x, 1, 32);
        float eN0 = __shfl_up(cN.w, 1, 32), eN1 = __shfl_down(cN.x, 1, 32);
        if (w0 == 0)   { eP0 = cP.y; eC0 = cC.y; eN0 = cN.y; }   // reflect -1 -> 1
        if (w0 == 124) { eP1 = cP.z; eC1 = cC.z; eN1 = cN.z; }   // reflect 128 -> 126

        const float VP[6] = {eP0, cP.x, cP.y, cP.z, cP.w, eP1};
        const float VC[6] = {eC0, cC.x, cC.y, cC.z, cC.w, eC1};
        const float VN[6] = {eN0, cN.x, cN.y, cN.z, cN.w, eN1};

        float o[4];
#pragma unroll
        for (int p = 0; p < 4; ++p) {
            float acc = 0.f;
#pragma unroll
            for (int t = 0; t < 3; ++t) {
                acc = fmaf(w9[t],     VP[p + t], acc);
                acc = fmaf(w9[3 + t], VC[p + t], acc);
                acc = fmaf(w9[6 + t], VN[p + t], acc);
            }
            o[p] = acc;
        }

        const size_t base = (size_t)plane * HWSZ + (size_t)h * WW + w0;
        v4f ov = {o[0], o[1], o[2], o[3]};
        v4f dv = {VC[1] - o[0], VC[2] - o[1], VC[3] - o[2], VC[4] - o[3]};
        __builtin_nontemporal_store(ov, (v4f*)(out + base));
        __builtin_nontemporal_store(dv, (v4f*)(out + NCHW + base));
    }
}

extern "C" void kernel_launch(void* const* d_in, const int* in_sizes, int n_in,
                              void* d_out, int out_size, void* d_ws, size_t ws_size,
                              hipStream_t stream) {
    const float* x       = (const float*)d_in[0];
    const float* conv_w  = (const float*)d_in[1];
    const float* gamma   = (const float*)d_in[2];
    const float* beta    = (const float*)d_in[3];
    const float* bn_mean = (const float*)d_in[4];
    const float* bn_var  = (const float*)d_in[5];
    float* out = (float*)d_out;

    int*   cnt     = (int*)d_ws;                       // 8 counters
    float* partial = (float*)((char*)d_ws + 128);      // 2048 band sums

    hipMemsetAsync(cnt, 0, 8 * sizeof(int), stream);   // capturable memset node
    dc_fused_kernel<<<NPLANE * 4, 256, 0, stream>>>(x, conv_w, gamma, beta,
                                                    bn_mean, bn_var, out,
                                                    partial, cnt);
}